// Round 2
// baseline (4803.377 us; speedup 1.0000x reference)
//
#include <hip/hip_runtime.h>
#include <hip/hip_bf16.h>
#include <stdint.h>

typedef __attribute__((ext_vector_type(8))) short bf16x8;
typedef __attribute__((ext_vector_type(4))) float f32x4;
typedef unsigned long long ull_t;

#define S_LEN 512
#define B_DIM 64
#define E_DIM 512
#define H_DIM 768
#define G4    3072      // 4H (one direction's gate width)
#define H2    1536      // 2H (combined hs row)
#define M_ROWS 32768    // S*B
#define CHUNK 128       // seq steps per X-chunk
#define CM    8192      // CHUNK*B rows per chunk
#define SLW   24        // cols per slice
#define KRES  640       // K columns resident in LDS
#define KREG  4         // remaining k-tiles (4*32 = 128) pinned in registers
#define WROW  648       // padded LDS weight row (shorts)
#define GWRD  3072      // 8B words per group h-block (16*768/4)
#define PWRD  12288     // 8B words per parity (4 groups)

__device__ __forceinline__ float sigmf_(float x) { return 1.0f / (1.0f + __expf(-x)); }
__device__ __forceinline__ float tanhf2(float x) {
  x = fminf(fmaxf(x, -20.0f), 20.0f);
  float e = __expf(2.0f * x);
  return (e - 1.0f) / (e + 1.0f);
}
__device__ __forceinline__ float bfu(unsigned short u) { return __uint_as_float((unsigned)u << 16); }
__device__ __forceinline__ unsigned short packbf(float a) {
  __hip_bfloat16 t = __float2bfloat16(a);
  unsigned short b;
  __builtin_memcpy(&b, &t, 2);
  return b;
}

// ---------------- embedding gather + cast to bf16 ----------------
__global__ __launch_bounds__(256) void k_gather(const int* __restrict__ tokens,
                                                const float* __restrict__ emb,
                                                __hip_bfloat16* __restrict__ out) {
  const int t = blockIdx.x * 256 + threadIdx.x;
  const int e0 = t * 8;
  const int row = e0 >> 9;
  const int k = e0 & 511;
  const int tok = tokens[row];
  const float4* p = (const float4*)(emb + (size_t)tok * E_DIM + k);
  const float4 v0 = p[0], v1 = p[1];
  __align__(16) __hip_bfloat16 tmp[8];
  tmp[0] = __float2bfloat16(v0.x); tmp[1] = __float2bfloat16(v0.y);
  tmp[2] = __float2bfloat16(v0.z); tmp[3] = __float2bfloat16(v0.w);
  tmp[4] = __float2bfloat16(v1.x); tmp[5] = __float2bfloat16(v1.y);
  tmp[6] = __float2bfloat16(v1.z); tmp[7] = __float2bfloat16(v1.w);
  *(bf16x8*)(out + (size_t)t * 8) = *(const bf16x8*)tmp;
}

// ---------------- fp32 -> bf16 transpose (LDS tiled): dst[c*Rs+r]=src[r*Cs+c] ----------------
__global__ __launch_bounds__(256) void k_transpose_cast(const float* __restrict__ src,
                                                        __hip_bfloat16* __restrict__ dst,
                                                        int Rs, int Cs) {
  __shared__ float tile[32][33];
  const int tx = threadIdx.x & 31, ty = threadIdx.x >> 5;
  const int c0 = blockIdx.x * 32, r0 = blockIdx.y * 32;
  #pragma unroll
  for (int i = ty; i < 32; i += 8)
    tile[i][tx] = src[(size_t)(r0 + i) * Cs + c0 + tx];
  __syncthreads();
  #pragma unroll
  for (int i = ty; i < 32; i += 8)
    dst[(size_t)(c0 + i) * Rs + r0 + tx] = __float2bfloat16(tile[tx][i]);
}

// ---------------- combined bias for one direction: bi + bh ----------------
__global__ __launch_bounds__(256) void k_bias(const float* __restrict__ bi,
                                              const float* __restrict__ bh,
                                              float* __restrict__ bias) {
  const int n = blockIdx.x * 256 + threadIdx.x;
  bias[n] = bi[n] + bh[n];
}

// ---------------- chunk GEMM: Xc[8192,3072] = EmbChunk[8192,512] @ WiT^T + bias ----------------
__global__ __launch_bounds__(256) void k_gemm_x(const __hip_bfloat16* __restrict__ A,
                                                const __hip_bfloat16* __restrict__ BT,
                                                const float* __restrict__ bias,
                                                __hip_bfloat16* __restrict__ C) {
  __shared__ __align__(16) __hip_bfloat16 As[128][40];
  __shared__ __align__(16) __hip_bfloat16 Bs[128][40];
  const int tid = threadIdx.x;
  const int wave = tid >> 6, lane = tid & 63;
  const int q = lane >> 4, lr = lane & 15;
  const int wm = (wave >> 1) * 64, wn = (wave & 1) * 64;
  const int m0 = blockIdx.y * 128, n0 = blockIdx.x * 128;
  const int srow = tid >> 2, skseg = (tid & 3) * 8;

  f32x4 acc[4][4];
  #pragma unroll
  for (int i = 0; i < 4; ++i)
    #pragma unroll
    for (int j = 0; j < 4; ++j) { f32x4 z = {0.f, 0.f, 0.f, 0.f}; acc[i][j] = z; }

  for (int kt = 0; kt < 16; ++kt) {
    __syncthreads();
    const int kbase = kt * 32 + skseg;
    *(bf16x8*)&As[srow][skseg]      = *(const bf16x8*)(A + (size_t)(m0 + srow) * E_DIM + kbase);
    *(bf16x8*)&As[srow + 64][skseg] = *(const bf16x8*)(A + (size_t)(m0 + srow + 64) * E_DIM + kbase);
    *(bf16x8*)&Bs[srow][skseg]      = *(const bf16x8*)(BT + (size_t)(n0 + srow) * E_DIM + kbase);
    *(bf16x8*)&Bs[srow + 64][skseg] = *(const bf16x8*)(BT + (size_t)(n0 + srow + 64) * E_DIM + kbase);
    __syncthreads();
    bf16x8 af[4], bfr[4];
    #pragma unroll
    for (int mt = 0; mt < 4; ++mt) af[mt] = *(const bf16x8*)&As[wm + mt * 16 + lr][q * 8];
    #pragma unroll
    for (int nt = 0; nt < 4; ++nt) bfr[nt] = *(const bf16x8*)&Bs[wn + nt * 16 + lr][q * 8];
    #pragma unroll
    for (int mt = 0; mt < 4; ++mt)
      #pragma unroll
      for (int nt = 0; nt < 4; ++nt)
        acc[mt][nt] = __builtin_amdgcn_mfma_f32_16x16x32_bf16(af[mt], bfr[nt], acc[mt][nt], 0, 0, 0);
  }
  #pragma unroll
  for (int mt = 0; mt < 4; ++mt) {
    #pragma unroll
    for (int nt = 0; nt < 4; ++nt) {
      const int col = n0 + wn + nt * 16 + lr;
      const float bv = bias[col];
      #pragma unroll
      for (int i = 0; i < 4; ++i) {
        const int row = m0 + wm + mt * 16 + q * 4 + i;
        C[(size_t)row * G4 + col] = __float2bfloat16(acc[mt][nt][i] + bv);
      }
    }
  }
}

// ---------------- forward LSTM scan: flag-gated bulk exchange, LDS-resident weights -------
// 128 WGs = 4 independent rings (16 batch rows) x 32 col-slices (24 cols).
// Per step: 32 threads poll 32 per-slice flags (ONE word each; ~128x less LLC spin
// traffic than per-word tag polling) -> barrier -> bulk-load the 24KB h block as
// packed 4xbf16 b64 words -> ds_write_b64 stage (no ushort scatter) -> GEMM ->
// nonlin -> data stores -> barrier (implicit vmcnt(0) acks stores at LLC) ->
// flag = step+1. Double-buffer safety: producer overwrites slot (s-1)&1 only after
// its step-s poll saw all flags >= s, which implies every peer finished READING
// h_{s-1} (stage precedes produce in each peer's step s-1).
__global__ __launch_bounds__(256, 1) void k_fwd_scan(const __hip_bfloat16* __restrict__ X,    // [8192,3072] chunk
                                                     const __hip_bfloat16* __restrict__ WhTf, // [3072,768]
                                                     ull_t* __restrict__ hdata,               // [2][4][16][192] b64
                                                     int* __restrict__ flags,                 // [4][32] x16 pad
                                                     __hip_bfloat16* __restrict__ Hs,         // [32768,1536]
                                                     float* __restrict__ cstate,              // [64,768]
                                                     float* __restrict__ hT,                  // [64,768]
                                                     int chunk) {
  const int bx = blockIdx.x;
  const int group = bx >> 5;           // ring: batch rows [16g, 16g+16)
  const int slice = bx & 31;           // cols [24*slice, 24*slice+24)
  const int r0 = group * 16;
  const int j0 = slice * SLW;
  const int tid = threadIdx.x;
  const int w = tid >> 6;              // wave = gate index (r,f,g,o)
  const int lane = tid & 63;
  const int q = lane >> 4, lr = lane & 15;
  const int base = chunk * CHUNK;

  const int onr = tid / 6;             // nonlin: batch row (tid<96)
  const int onw = tid - onr * 6;       // nonlin: 8B word within slice
  const int col0 = onw * 4;            // first owned col within slice

  __shared__ __align__(16) unsigned short wlds[4 * SLW * WROW];  // 124,416 B weight slice
  __shared__ __align__(16) unsigned short h_stage[16][776];      //  24,832 B
  __shared__ float g_lds[4][16][26];                             //   6,656 B (total 155,904)

  // ---- stage LDS-resident weights once ----
  for (int c = tid; c < 96 * (KRES / 8); c += 256) {
    const int r = c / (KRES / 8), k8 = c % (KRES / 8);
    const int gate = r / SLW, n = r % SLW;
    const float4 v = *(const float4*)(WhTf + (size_t)(gate * H_DIM + j0 + n) * H_DIM + k8 * 8);
    *(float4*)(wlds + (size_t)r * WROW + k8 * 8) = v;
  }

  // ---- K-tail weight fragments pinned in registers (step-invariant) ----
  const int wn0 = lr;                  // n-tile 0: cols 0..15
  const int wn1 = 16 + (lr & 7);       // n-tile 1: cols 16..23 (lanes lr>=8 duplicate)
  bf16x8 wr0[KREG], wr1[KREG];
  #pragma unroll
  for (int kk = 0; kk < KREG; ++kk) {
    const int ko = KRES + kk * 32 + q * 8;
    wr0[kk] = *(const bf16x8*)(WhTf + (size_t)(w * H_DIM + j0 + wn0) * H_DIM + ko);
    wr1[kk] = *(const bf16x8*)(WhTf + (size_t)(w * H_DIM + j0 + wn1) * H_DIM + ko);
  }

  // persistent c in registers: thread (tid<96) owns (onr, col0..col0+3)
  float cr[4] = {0.f, 0.f, 0.f, 0.f};
  if (tid < 96) {
    const float4 cv = *(const float4*)(cstate + (size_t)(r0 + onr) * H_DIM + j0 + col0);
    cr[0] = cv.x; cr[1] = cv.y; cr[2] = cv.z; cr[3] = cv.w;
  }

  // step-invariant LDS staging byte offsets (12 b64 words per thread)
  int soff[12];
  #pragma unroll
  for (int i = 0; i < 12; ++i) {
    const int wd = tid + 256 * i;
    soff[i] = (wd / 192) * 1552 + (wd % 192) * 8;
  }
  ull_t* const hg = hdata + (size_t)group * GWRD;
  __syncthreads();

  for (int s = 0; s < CHUNK; ++s) {
    const int gs = base + s;

    // ---- X prefetch (independent of h; overlaps poll + flag visibility) ----
    ull_t xv[4] = {0, 0, 0, 0};
    if (tid < 96) {
      const ull_t* xp = (const ull_t*)(X + ((size_t)s * B_DIM + r0 + onr) * G4 + j0 + col0);
      #pragma unroll
      for (int g = 0; g < 4; ++g) xv[g] = xp[(size_t)g * 192];
    }

    // ---- discovery: 32 threads poll 32 per-slice flags ----
    if (tid < 32) {
      const int* fp = flags + ((group << 5) + tid) * 16;
      long guard = 0;
      while (__hip_atomic_load(fp, __ATOMIC_RELAXED, __HIP_MEMORY_SCOPE_AGENT) < gs) {
        __builtin_amdgcn_s_sleep(1);
        if (++guard > (1L << 22)) break;   // fail visibly, never hang
      }
    }
    __syncthreads();   // B1: all slices published h_gs

    // ---- bulk load h_gs (24KB packed bf16) + LDS stage ----
    {
      const ull_t* hsrc = hg + ((size_t)(gs & 1) * PWRD) + tid;
      ull_t hv[12];
      #pragma unroll
      for (int i = 0; i < 12; ++i)
        hv[i] = __hip_atomic_load(hsrc + 256 * i, __ATOMIC_RELAXED, __HIP_MEMORY_SCOPE_AGENT);
      #pragma unroll
      for (int i = 0; i < 12; ++i)
        *(ull_t*)((char*)&h_stage[0][0] + soff[i]) = hv[i];
    }
    __syncthreads();   // B2: h staged

    // ---- hidden GEMM for gate w: [16,768] x [768,24] from LDS + reg weights ----
    f32x4 acc0 = {0.f, 0.f, 0.f, 0.f};
    f32x4 acc1 = {0.f, 0.f, 0.f, 0.f};
    {
      const unsigned short* wb = wlds + (size_t)w * SLW * WROW;
      #pragma unroll
      for (int kt = 0; kt < KRES / 32; ++kt) {
        const int ko = kt * 32 + q * 8;
        const bf16x8 a  = *(const bf16x8*)&h_stage[lr][ko];
        const bf16x8 b0 = *(const bf16x8*)(wb + (size_t)wn0 * WROW + ko);
        const bf16x8 b1 = *(const bf16x8*)(wb + (size_t)wn1 * WROW + ko);
        acc0 = __builtin_amdgcn_mfma_f32_16x16x32_bf16(a, b0, acc0, 0, 0, 0);
        acc1 = __builtin_amdgcn_mfma_f32_16x16x32_bf16(a, b1, acc1, 0, 0, 0);
      }
      #pragma unroll
      for (int kk = 0; kk < KREG; ++kk) {
        const bf16x8 a = *(const bf16x8*)&h_stage[lr][KRES + kk * 32 + q * 8];
        acc0 = __builtin_amdgcn_mfma_f32_16x16x32_bf16(a, wr0[kk], acc0, 0, 0, 0);
        acc1 = __builtin_amdgcn_mfma_f32_16x16x32_bf16(a, wr1[kk], acc1, 0, 0, 0);
      }
    }
    #pragma unroll
    for (int i = 0; i < 4; ++i) g_lds[w][q * 4 + i][lr] = acc0[i];
    if (lr < 8) {
      #pragma unroll
      for (int i = 0; i < 4; ++i) g_lds[w][q * 4 + i][16 + lr] = acc1[i];
    }
    __syncthreads();   // B3: gates ready

    // ---- nonlinearity + c/h update: thread owns (onr, col0..col0+3) ----
    if (tid < 96) {
      unsigned short hb[4];
      #pragma unroll
      for (int j = 0; j < 4; ++j) {
        const float rv = g_lds[0][onr][col0 + j] + bfu((unsigned short)(xv[0] >> (16 * j)));
        const float fv = g_lds[1][onr][col0 + j] + bfu((unsigned short)(xv[1] >> (16 * j)));
        const float gv = g_lds[2][onr][col0 + j] + bfu((unsigned short)(xv[2] >> (16 * j)));
        const float ov = g_lds[3][onr][col0 + j] + bfu((unsigned short)(xv[3] >> (16 * j)));
        const float c = sigmf_(fv) * cr[j] + sigmf_(rv) * tanhf2(gv);
        cr[j] = c;
        hb[j] = packbf(sigmf_(ov) * tanhf2(c));
      }
      const ull_t wv = (ull_t)hb[0] | ((ull_t)hb[1] << 16) | ((ull_t)hb[2] << 32) | ((ull_t)hb[3] << 48);
      __hip_atomic_store(hg + ((size_t)((gs + 1) & 1) * PWRD) + (size_t)onr * 192 + slice * 6 + onw,
                         wv, __ATOMIC_RELAXED, __HIP_MEMORY_SCOPE_AGENT);
      *(ull_t*)(Hs + ((size_t)gs * B_DIM + r0 + onr) * H2 + j0 + col0) = wv;
      if (chunk == 3 && s == CHUNK - 1) {
        float4 hv4;
        hv4.x = bfu(hb[0]); hv4.y = bfu(hb[1]); hv4.z = bfu(hb[2]); hv4.w = bfu(hb[3]);
        *(float4*)(hT + (size_t)(r0 + onr) * H_DIM + j0 + col0) = hv4;
      }
    }
    __syncthreads();   // B4: implicit vmcnt(0) -> all waves' data stores acked at LLC
    if (tid == 0)
      __hip_atomic_store(flags + ((group << 5) + slice) * 16, gs + 1,
                         __ATOMIC_RELEASE, __HIP_MEMORY_SCOPE_AGENT);
  }

  // persist c for next chunk
  if (tid < 96) {
    float4 cv; cv.x = cr[0]; cv.y = cr[1]; cv.z = cr[2]; cv.w = cr[3];
    *(float4*)(cstate + (size_t)(r0 + onr) * H_DIM + j0 + col0) = cv;
  }
}

// ---------------- hTW[b,n] = hT[b,:] @ Wh_b[:,n] ----------------
__global__ __launch_bounds__(256) void k_hTW(const float* __restrict__ hT,
                                             const float* __restrict__ Whb,
                                             float* __restrict__ hTW) {
  const int b = blockIdx.y;
  const int n = blockIdx.x * 256 + threadIdx.x;
  __shared__ float hs[768];
  for (int i = threadIdx.x; i < 768; i += 256) hs[i] = hT[b * 768 + i];
  __syncthreads();
  float acc = 0.f;
  #pragma unroll 4
  for (int k = 0; k < 768; ++k) acc += hs[k] * Whb[(size_t)k * G4 + n];
  hTW[(size_t)b * G4 + n] = acc;
}

// ---------------- backward scan (one chunk, reverse): independent chains ----------------
__global__ __launch_bounds__(256) void k_bwd_scan(const __hip_bfloat16* __restrict__ X,
                                                  const float* __restrict__ hTW,
                                                  __hip_bfloat16* __restrict__ Hs,
                                                  float* __restrict__ c2state,
                                                  int chunk) {
  const int t = blockIdx.x * 256 + threadIdx.x;    // 49152
  const int b = t / H_DIM;
  const int j = t % H_DIM;
  const int base = chunk * CHUNK;
  const float hw0 = hTW[(size_t)b * G4 + j];
  const float hw1 = hTW[(size_t)b * G4 + 768 + j];
  const float hw2 = hTW[(size_t)b * G4 + 1536 + j];
  const float hw3 = hTW[(size_t)b * G4 + 2304 + j];
  float c2 = c2state[t];
  for (int s = CHUNK - 1; s >= 0; --s) {
    const size_t xb = ((size_t)s * B_DIM + b) * G4 + j;
    const float r = sigmf_(__bfloat162float(X[xb]) + hw0);
    const float f = sigmf_(__bfloat162float(X[xb + 768]) + hw1);
    const float g = tanhf2(__bfloat162float(X[xb + 1536]) + hw2);
    const float o = sigmf_(__bfloat162float(X[xb + 2304]) + hw3);
    c2 = f * c2 + r * g;
    Hs[((size_t)(base + s) * B_DIM + b) * H2 + H_DIM + j] = __float2bfloat16(o * tanhf2(c2));
  }
  c2state[t] = c2;
}

// ---------------- output: out[i,l] = Hs[i,:] @ Wout + bout (+pad bias) ----------------
__global__ __launch_bounds__(256) void k_out(const __hip_bfloat16* __restrict__ Hs,
                                             const float* __restrict__ Wout,
                                             const float* __restrict__ bout,
                                             const int* __restrict__ tokens,
                                             float* __restrict__ out) {
  __shared__ float rowbuf[8][1536];
  const int r0 = blockIdx.x * 8;
  const int tid = threadIdx.x;
  for (int idx = tid; idx < 8 * 1536; idx += 256) {
    const int rr = idx / 1536, k = idx % 1536;
    rowbuf[rr][k] = __bfloat162float(Hs[(size_t)(r0 + rr) * H2 + k]);
  }
  __syncthreads();
  const int l = tid & 31, rr = tid >> 5;
  float acc = bout[l];
  #pragma unroll 8
  for (int k = 0; k < 1536; ++k) acc += rowbuf[rr][k] * Wout[k * 32 + l];
  const int row = r0 + rr;
  if (l == 0 && tokens[row] == 1) acc += 10000.0f;
  out[(size_t)row * 32 + l] = acc;
}

// ---------------- host launcher ----------------
extern "C" void kernel_launch(void* const* d_in, const int* in_sizes, int n_in,
                              void* d_out, int out_size, void* d_ws, size_t ws_size,
                              hipStream_t stream) {
  const int*   tokens = (const int*)d_in[0];
  const float* emb    = (const float*)d_in[2];
  const float* Wi_f   = (const float*)d_in[3];
  const float* bi_f   = (const float*)d_in[4];
  const float* Wh_f   = (const float*)d_in[5];
  const float* bh_f   = (const float*)d_in[6];
  const float* Wi_b   = (const float*)d_in[7];
  const float* bi_b   = (const float*)d_in[8];
  const float* Wh_b   = (const float*)d_in[9];
  const float* bh_b   = (const float*)d_in[10];
  const float* Wout   = (const float*)d_in[11];
  const float* bout   = (const float*)d_in[12];
  float* out = (float*)d_out;
  char* ws = (char*)d_ws;

  size_t off = 0;
  auto alloc = [&](size_t bytes) { size_t o = off; off += (bytes + 255) & ~(size_t)255; return o; };
  const size_t oHs    = alloc((size_t)M_ROWS * H2 * 2);        // 100.7 MB
  const size_t oX     = alloc((size_t)CM * G4 * 2);            // 50.3 MB
  const size_t oEmb   = alloc((size_t)M_ROWS * E_DIM * 2);     // 33.6 MB
  const size_t oWiT   = alloc((size_t)G4 * E_DIM * 2);         // 3.1 MB
  const size_t oWhTf  = alloc((size_t)G4 * H_DIM * 2);         // 4.7 MB
  const size_t oBias  = alloc((size_t)G4 * 4);
  const size_t oHdat  = alloc((size_t)2 * PWRD * 8);           // 192 KB packed h
  const size_t oFlag  = alloc((size_t)4 * 32 * 16 * 4);        // 8 KB flags
  const size_t oCst   = alloc((size_t)B_DIM * H_DIM * 4);
  const size_t oHT    = alloc((size_t)B_DIM * H_DIM * 4);
  const size_t oHTW   = alloc((size_t)B_DIM * G4 * 4);
  const size_t oC2    = alloc((size_t)B_DIM * H_DIM * 4);
  (void)ws_size; (void)in_sizes; (void)n_in; (void)out_size;

  __hip_bfloat16* Hs   = (__hip_bfloat16*)(ws + oHs);
  __hip_bfloat16* X    = (__hip_bfloat16*)(ws + oX);
  __hip_bfloat16* Emb  = (__hip_bfloat16*)(ws + oEmb);
  __hip_bfloat16* WiT  = (__hip_bfloat16*)(ws + oWiT);
  __hip_bfloat16* WhTf = (__hip_bfloat16*)(ws + oWhTf);
  float*          Bias = (float*)(ws + oBias);
  ull_t*          Hdat = (ull_t*)(ws + oHdat);
  int*            Flag = (int*)(ws + oFlag);
  float*          Cst  = (float*)(ws + oCst);
  float*          HT   = (float*)(ws + oHT);
  float*          HTW  = (float*)(ws + oHTW);
  float*          C2   = (float*)(ws + oC2);

  hipMemsetAsync(ws + oHdat, 0, (size_t)2 * PWRD * 8, stream);   // h_0 = 0
  hipMemsetAsync(ws + oFlag, 0, (size_t)4 * 32 * 16 * 4, stream); // flags = 0 (h_0 published)
  hipMemsetAsync(ws + oCst, 0, (size_t)B_DIM * H_DIM * 4, stream);
  hipMemsetAsync(ws + oC2, 0, (size_t)B_DIM * H_DIM * 4, stream);

  k_gather<<<8192, 256, 0, stream>>>(tokens, emb, Emb);
  k_transpose_cast<<<dim3(96, 24), 256, 0, stream>>>(Wh_f, WhTf, 768, 3072);

  // ---- forward direction: 4 chunks of (GEMM -> scan) ----
  k_transpose_cast<<<dim3(96, 16), 256, 0, stream>>>(Wi_f, WiT, 512, 3072);
  k_bias<<<12, 256, 0, stream>>>(bi_f, bh_f, Bias);
  for (int c = 0; c < 4; ++c) {
    k_gemm_x<<<dim3(24, 64), 256, 0, stream>>>(Emb + (size_t)c * CM * E_DIM, WiT, Bias, X);
    k_fwd_scan<<<128, 256, 0, stream>>>(X, WhTf, Hdat, Flag, Hs, Cst, HT, c);
  }

  // ---- backward direction: hT@Wh_b once, then 4 chunks in reverse ----
  k_hTW<<<dim3(12, 64), 256, 0, stream>>>(HT, Wh_b, HTW);
  k_transpose_cast<<<dim3(96, 16), 256, 0, stream>>>(Wi_b, WiT, 512, 3072);
  k_bias<<<12, 256, 0, stream>>>(bi_b, bh_b, Bias);
  for (int c = 3; c >= 0; --c) {
    k_gemm_x<<<dim3(24, 64), 256, 0, stream>>>(Emb + (size_t)c * CM * E_DIM, WiT, Bias, X);
    k_bwd_scan<<<192, 256, 0, stream>>>(X, HTW, Hs, C2, c);
  }

  k_out<<<4096, 256, 0, stream>>>(Hs, Wout, bout, tokens, out);
}

// Round 3
// 4232.383 us; speedup vs baseline: 1.1349x; 1.1349x over previous
//
#include <hip/hip_runtime.h>
#include <hip/hip_bf16.h>
#include <stdint.h>

typedef __attribute__((ext_vector_type(8))) short bf16x8;
typedef __attribute__((ext_vector_type(4))) float f32x4;
typedef unsigned long long ull_t;

#define S_LEN 512
#define B_DIM 64
#define E_DIM 512
#define H_DIM 768
#define G4    3072      // 4H (one direction's gate width)
#define H2    1536      // 2H (combined hs row)
#define M_ROWS 32768    // S*B
#define CHUNK 128       // seq steps per X-chunk
#define CM    8192      // CHUNK*B rows per chunk
#define NSL   16        // slices per ring
#define SLW   48        // cols per slice (3 full 16-wide N-tiles)
#define WPR   256       // packed words per h row (256*3 = 768 cols)
#define RWRD  4096      // words per ring per parity (16 rows * 256)
#define PSTR  16384     // words per parity (4 rings)
#define KRES  288       // K columns resident in LDS (9 k-tiles)
#define KTL   9         // LDS k-tiles
#define KREG  15        // register k-tiles (15*32 = 480; 288+480 = 768)
#define WROW  296       // padded LDS weight row (shorts): 288 + 8

__device__ __forceinline__ float sigmf_(float x) { return 1.0f / (1.0f + __expf(-x)); }
__device__ __forceinline__ float tanhf2(float x) {
  x = fminf(fmaxf(x, -20.0f), 20.0f);
  float e = __expf(2.0f * x);
  return (e - 1.0f) / (e + 1.0f);
}
__device__ __forceinline__ float bfu(unsigned short u) { return __uint_as_float((unsigned)u << 16); }
__device__ __forceinline__ unsigned short packbf(float a) {
  __hip_bfloat16 t = __float2bfloat16(a);
  unsigned short b;
  __builtin_memcpy(&b, &t, 2);
  return b;
}

// ---------------- embedding gather + cast to bf16 ----------------
__global__ __launch_bounds__(256) void k_gather(const int* __restrict__ tokens,
                                                const float* __restrict__ emb,
                                                __hip_bfloat16* __restrict__ out) {
  const int t = blockIdx.x * 256 + threadIdx.x;
  const int e0 = t * 8;
  const int row = e0 >> 9;
  const int k = e0 & 511;
  const int tok = tokens[row];
  const float4* p = (const float4*)(emb + (size_t)tok * E_DIM + k);
  const float4 v0 = p[0], v1 = p[1];
  __align__(16) __hip_bfloat16 tmp[8];
  tmp[0] = __float2bfloat16(v0.x); tmp[1] = __float2bfloat16(v0.y);
  tmp[2] = __float2bfloat16(v0.z); tmp[3] = __float2bfloat16(v0.w);
  tmp[4] = __float2bfloat16(v1.x); tmp[5] = __float2bfloat16(v1.y);
  tmp[6] = __float2bfloat16(v1.z); tmp[7] = __float2bfloat16(v1.w);
  *(bf16x8*)(out + (size_t)t * 8) = *(const bf16x8*)tmp;
}

// ---------------- fp32 -> bf16 transpose (LDS tiled): dst[c*Rs+r]=src[r*Cs+c] ----------------
__global__ __launch_bounds__(256) void k_transpose_cast(const float* __restrict__ src,
                                                        __hip_bfloat16* __restrict__ dst,
                                                        int Rs, int Cs) {
  __shared__ float tile[32][33];
  const int tx = threadIdx.x & 31, ty = threadIdx.x >> 5;
  const int c0 = blockIdx.x * 32, r0 = blockIdx.y * 32;
  #pragma unroll
  for (int i = ty; i < 32; i += 8)
    tile[i][tx] = src[(size_t)(r0 + i) * Cs + c0 + tx];
  __syncthreads();
  #pragma unroll
  for (int i = ty; i < 32; i += 8)
    dst[(size_t)(c0 + i) * Rs + r0 + tx] = __float2bfloat16(tile[tx][i]);
}

// ---------------- combined bias for one direction: bi + bh ----------------
__global__ __launch_bounds__(256) void k_bias(const float* __restrict__ bi,
                                              const float* __restrict__ bh,
                                              float* __restrict__ bias) {
  const int n = blockIdx.x * 256 + threadIdx.x;
  bias[n] = bi[n] + bh[n];
}

// ---------------- chunk GEMM: Xc[8192,3072] = EmbChunk[8192,512] @ WiT^T + bias ----------------
__global__ __launch_bounds__(256) void k_gemm_x(const __hip_bfloat16* __restrict__ A,
                                                const __hip_bfloat16* __restrict__ BT,
                                                const float* __restrict__ bias,
                                                __hip_bfloat16* __restrict__ C) {
  __shared__ __align__(16) __hip_bfloat16 As[128][40];
  __shared__ __align__(16) __hip_bfloat16 Bs[128][40];
  const int tid = threadIdx.x;
  const int wave = tid >> 6, lane = tid & 63;
  const int q = lane >> 4, lr = lane & 15;
  const int wm = (wave >> 1) * 64, wn = (wave & 1) * 64;
  const int m0 = blockIdx.y * 128, n0 = blockIdx.x * 128;
  const int srow = tid >> 2, skseg = (tid & 3) * 8;

  f32x4 acc[4][4];
  #pragma unroll
  for (int i = 0; i < 4; ++i)
    #pragma unroll
    for (int j = 0; j < 4; ++j) { f32x4 z = {0.f, 0.f, 0.f, 0.f}; acc[i][j] = z; }

  for (int kt = 0; kt < 16; ++kt) {
    __syncthreads();
    const int kbase = kt * 32 + skseg;
    *(bf16x8*)&As[srow][skseg]      = *(const bf16x8*)(A + (size_t)(m0 + srow) * E_DIM + kbase);
    *(bf16x8*)&As[srow + 64][skseg] = *(const bf16x8*)(A + (size_t)(m0 + srow + 64) * E_DIM + kbase);
    *(bf16x8*)&Bs[srow][skseg]      = *(const bf16x8*)(BT + (size_t)(n0 + srow) * E_DIM + kbase);
    *(bf16x8*)&Bs[srow + 64][skseg] = *(const bf16x8*)(BT + (size_t)(n0 + srow + 64) * E_DIM + kbase);
    __syncthreads();
    bf16x8 af[4], bfr[4];
    #pragma unroll
    for (int mt = 0; mt < 4; ++mt) af[mt] = *(const bf16x8*)&As[wm + mt * 16 + lr][q * 8];
    #pragma unroll
    for (int nt = 0; nt < 4; ++nt) bfr[nt] = *(const bf16x8*)&Bs[wn + nt * 16 + lr][q * 8];
    #pragma unroll
    for (int mt = 0; mt < 4; ++mt)
      #pragma unroll
      for (int nt = 0; nt < 4; ++nt)
        acc[mt][nt] = __builtin_amdgcn_mfma_f32_16x16x32_bf16(af[mt], bfr[nt], acc[mt][nt], 0, 0, 0);
  }
  #pragma unroll
  for (int mt = 0; mt < 4; ++mt) {
    #pragma unroll
    for (int nt = 0; nt < 4; ++nt) {
      const int col = n0 + wn + nt * 16 + lr;
      const float bv = bias[col];
      #pragma unroll
      for (int i = 0; i < 4; ++i) {
        const int row = m0 + wm + mt * 16 + q * 4 + i;
        C[(size_t)row * G4 + col] = __float2bfloat16(acc[mt][nt][i] + bv);
      }
    }
  }
}

// ---------------- forward LSTM scan: tag-in-data systolic, 64 WGs, reg+LDS weights ------
// 64 WGs = 4 independent rings (16 batch rows) x 16 col-slices (48 cols).
// h exchanged as 8B words [tag16 | 3 x bf16] via relaxed agent atomics: ONE LLC
// round trip per step (data arrival IS the signal; R2's flag->bulk chain cost 2 RTs).
// Per-WG weights: K<288 in LDS (padded rows), K 288..768 in 180 VGPRs/thread
// (step-invariant MFMA B-fragments). Poll: 16 CONSECUTIVE words/thread, no sleep,
// need-mask; staging strips tags in registers -> 6x ds_write_b128 (no b16 scatter).
// Double-buffer safety: producer overwrites parity p at step gs only after its
// step-gs poll saw tag gs from all slices => every peer passed B1(gs) => every
// peer's reads of parity p (step gs-1) completed. Same proof as verified rounds.
__global__ __launch_bounds__(256, 1) void k_fwd_scan(const __hip_bfloat16* __restrict__ X,    // [8192,3072] chunk
                                                     const __hip_bfloat16* __restrict__ WhTf, // [3072,768]
                                                     ull_t* __restrict__ hbuf,                // [2][4][16][256]
                                                     __hip_bfloat16* __restrict__ Hs,         // [32768,1536]
                                                     float* __restrict__ cstate,              // [64,768]
                                                     float* __restrict__ hT,                  // [64,768]
                                                     int chunk) {
  const int bx = blockIdx.x;
  const int group = bx >> 4;           // ring: batch rows [16g, 16g+16)
  const int slice = bx & 15;           // cols [48*slice, 48*slice+48)
  const int r0 = group * 16;
  const int j0 = slice * SLW;
  const int tid = threadIdx.x;
  const int w = tid >> 6;              // wave = gate index (r,f,g,o)
  const int lane = tid & 63;
  const int q = lane >> 4, lr = lane & 15;
  const int base = chunk * CHUNK;

  const int prow = tid >> 4;           // poll/nonlin: batch row within group (0..15)
  const int pw   = tid & 15;           // poll: 16-word chunk id; nonlin: word in slice
  const int col0 = 3 * pw;             // nonlin: first owned col within slice (0..45)

  __shared__ __align__(16) unsigned short wlds[192 * WROW];   // 113,664 B (K<288 weights)
  __shared__ __align__(16) unsigned short h_stage[16][776];   //  24,832 B
  __shared__ float g_lds[4][16][50];                          //  12,800 B (151,296 total)

  // ---- stage LDS-resident weight K-block once: row r = gate*48+col ----
  for (int c = tid; c < 192 * (KRES / 8); c += 256) {
    const int r = c / (KRES / 8), k8 = c % (KRES / 8);
    const int gate = r / SLW, n = r % SLW;
    const float4 v = *(const float4*)(WhTf + (size_t)(gate * H_DIM + j0 + n) * H_DIM + k8 * 8);
    *(float4*)(wlds + (size_t)r * WROW + k8 * 8) = v;
  }

  // ---- K-tail weight fragments pinned in registers (step-invariant) ----
  // lane (q,lr) of wave w holds B[k=KRES+kk*32+q*8 ..+7][col=j0+nt*16+lr]
  bf16x8 wreg[3][KREG];
  #pragma unroll
  for (int nt = 0; nt < 3; ++nt)
    #pragma unroll
    for (int kk = 0; kk < KREG; ++kk)
      wreg[nt][kk] = *(const bf16x8*)(WhTf + (size_t)(w * H_DIM + j0 + nt * 16 + lr) * H_DIM
                                      + KRES + kk * 32 + q * 8);

  // persistent c in registers: thread owns (prow, col0..col0+2)
  float cr[3];
  {
    const float* cs = cstate + (size_t)(r0 + prow) * H_DIM + j0 + col0;
    cr[0] = cs[0]; cr[1] = cs[1]; cr[2] = cs[2];
  }
  __syncthreads();

  for (int s = 0; s < CHUNK; ++s) {
    const int gs = base + s;

    // ---- X loads for this step (independent of h; overlap the poll) ----
    unsigned short xs[4][3];
    {
      const unsigned short* xp = (const unsigned short*)(X + ((size_t)s * B_DIM + r0 + prow) * G4 + j0 + col0);
      #pragma unroll
      for (int g = 0; g < 4; ++g)
        #pragma unroll
        for (int j = 0; j < 3; ++j) xs[g][j] = xp[g * H_DIM + j];
    }

    // ---- poll 16 consecutive words (128B/thread) until all tags == gs ----
    ull_t v[16];
    {
      const ull_t* hc = hbuf + ((size_t)(gs & 1)) * PSTR + (size_t)group * RWRD
                      + (size_t)prow * WPR + pw * 16;
      const unsigned short expct = (unsigned short)gs;
      unsigned need = 0xFFFFu;
      long guard = 0;
      for (;;) {
        #pragma unroll
        for (int i = 0; i < 16; ++i)
          if (need & (1u << i))
            v[i] = __hip_atomic_load(hc + i, __ATOMIC_RELAXED, __HIP_MEMORY_SCOPE_AGENT);
        unsigned nn = 0;
        #pragma unroll
        for (int i = 0; i < 16; ++i)
          if ((need & (1u << i)) && ((unsigned short)v[i] != expct)) nn |= 1u << i;
        need = nn;
        if (!need) break;
        if (++guard > (1L << 22)) break;   // fail visibly, never hang
      }
    }
    // ---- strip tags in registers, stage as 6x b128 (cols 48*pw .. +47) ----
    {
      __align__(16) unsigned short hs48[48];
      #pragma unroll
      for (int i = 0; i < 16; ++i) {
        hs48[3 * i]     = (unsigned short)(v[i] >> 16);
        hs48[3 * i + 1] = (unsigned short)(v[i] >> 32);
        hs48[3 * i + 2] = (unsigned short)(v[i] >> 48);
      }
      #pragma unroll
      for (int jj = 0; jj < 6; ++jj)
        *(bf16x8*)&h_stage[prow][48 * pw + 8 * jj] = *(const bf16x8*)&hs48[8 * jj];
    }
    __syncthreads();   // B1: h staged

    // ---- hidden GEMM for gate w: [16 rows] x [768 k] x [48 cols] ----
    f32x4 acc[3];
    #pragma unroll
    for (int nt = 0; nt < 3; ++nt) { f32x4 z = {0.f, 0.f, 0.f, 0.f}; acc[nt] = z; }
    #pragma unroll
    for (int kt = 0; kt < KTL; ++kt) {
      const int ko = kt * 32 + q * 8;
      const bf16x8 a = *(const bf16x8*)&h_stage[lr][ko];
      #pragma unroll
      for (int nt = 0; nt < 3; ++nt) {
        const bf16x8 b = *(const bf16x8*)(wlds + (size_t)(w * SLW + nt * 16 + lr) * WROW + ko);
        acc[nt] = __builtin_amdgcn_mfma_f32_16x16x32_bf16(a, b, acc[nt], 0, 0, 0);
      }
    }
    #pragma unroll
    for (int kk = 0; kk < KREG; ++kk) {
      const bf16x8 a = *(const bf16x8*)&h_stage[lr][KRES + kk * 32 + q * 8];
      #pragma unroll
      for (int nt = 0; nt < 3; ++nt)
        acc[nt] = __builtin_amdgcn_mfma_f32_16x16x32_bf16(a, wreg[nt][kk], acc[nt], 0, 0, 0);
    }
    #pragma unroll
    for (int nt = 0; nt < 3; ++nt)
      #pragma unroll
      for (int i = 0; i < 4; ++i)
        g_lds[w][q * 4 + i][nt * 16 + lr] = acc[nt][i];
    __syncthreads();   // B2: gates ready

    // ---- nonlinearity + c/h update + publish: thread owns (prow, col0..col0+2) ----
    {
      float h[3];
      #pragma unroll
      for (int j = 0; j < 3; ++j) {
        const float rv = g_lds[0][prow][col0 + j] + bfu(xs[0][j]);
        const float fv = g_lds[1][prow][col0 + j] + bfu(xs[1][j]);
        const float gv = g_lds[2][prow][col0 + j] + bfu(xs[2][j]);
        const float ov = g_lds[3][prow][col0 + j] + bfu(xs[3][j]);
        const float c = sigmf_(fv) * cr[j] + sigmf_(rv) * tanhf2(gv);
        cr[j] = c;
        h[j] = sigmf_(ov) * tanhf2(c);
      }
      const unsigned short b0 = packbf(h[0]), b1 = packbf(h[1]), b2 = packbf(h[2]);
      const ull_t wv = (ull_t)(unsigned short)(gs + 1)
                     | ((ull_t)b0 << 16) | ((ull_t)b1 << 32) | ((ull_t)b2 << 48);
      __hip_atomic_store(hbuf + ((size_t)((gs + 1) & 1)) * PSTR + (size_t)group * RWRD
                         + (size_t)prow * WPR + slice * 16 + pw,
                         wv, __ATOMIC_RELAXED, __HIP_MEMORY_SCOPE_AGENT);
      unsigned short* hsp = (unsigned short*)(Hs + ((size_t)gs * B_DIM + r0 + prow) * H2 + j0 + col0);
      hsp[0] = b0; hsp[1] = b1; hsp[2] = b2;
      if (chunk == 3 && s == CHUNK - 1) {
        float* hp = hT + (size_t)(r0 + prow) * H_DIM + j0 + col0;
        hp[0] = h[0]; hp[1] = h[1]; hp[2] = h[2];
      }
    }
    // no barrier: next step's B1 orders h_stage/g_lds reuse
  }

  // persist c for next chunk
  {
    float* cs = cstate + (size_t)(r0 + prow) * H_DIM + j0 + col0;
    cs[0] = cr[0]; cs[1] = cr[1]; cs[2] = cr[2];
  }
}

// ---------------- hTW[b,n] = hT[b,:] @ Wh_b[:,n] ----------------
__global__ __launch_bounds__(256) void k_hTW(const float* __restrict__ hT,
                                             const float* __restrict__ Whb,
                                             float* __restrict__ hTW) {
  const int b = blockIdx.y;
  const int n = blockIdx.x * 256 + threadIdx.x;
  __shared__ float hs[768];
  for (int i = threadIdx.x; i < 768; i += 256) hs[i] = hT[b * 768 + i];
  __syncthreads();
  float acc = 0.f;
  #pragma unroll 4
  for (int k = 0; k < 768; ++k) acc += hs[k] * Whb[(size_t)k * G4 + n];
  hTW[(size_t)b * G4 + n] = acc;
}

// ---------------- backward scan (one chunk, reverse): independent chains ----------------
__global__ __launch_bounds__(256) void k_bwd_scan(const __hip_bfloat16* __restrict__ X,
                                                  const float* __restrict__ hTW,
                                                  __hip_bfloat16* __restrict__ Hs,
                                                  float* __restrict__ c2state,
                                                  int chunk) {
  const int t = blockIdx.x * 256 + threadIdx.x;    // 49152
  const int b = t / H_DIM;
  const int j = t % H_DIM;
  const int base = chunk * CHUNK;
  const float hw0 = hTW[(size_t)b * G4 + j];
  const float hw1 = hTW[(size_t)b * G4 + 768 + j];
  const float hw2 = hTW[(size_t)b * G4 + 1536 + j];
  const float hw3 = hTW[(size_t)b * G4 + 2304 + j];
  float c2 = c2state[t];
  for (int s = CHUNK - 1; s >= 0; --s) {
    const size_t xb = ((size_t)s * B_DIM + b) * G4 + j;
    const float r = sigmf_(__bfloat162float(X[xb]) + hw0);
    const float f = sigmf_(__bfloat162float(X[xb + 768]) + hw1);
    const float g = tanhf2(__bfloat162float(X[xb + 1536]) + hw2);
    const float o = sigmf_(__bfloat162float(X[xb + 2304]) + hw3);
    c2 = f * c2 + r * g;
    Hs[((size_t)(base + s) * B_DIM + b) * H2 + H_DIM + j] = __float2bfloat16(o * tanhf2(c2));
  }
  c2state[t] = c2;
}

// ---------------- output: out[i,l] = Hs[i,:] @ Wout + bout (+pad bias) ----------------
__global__ __launch_bounds__(256) void k_out(const __hip_bfloat16* __restrict__ Hs,
                                             const float* __restrict__ Wout,
                                             const float* __restrict__ bout,
                                             const int* __restrict__ tokens,
                                             float* __restrict__ out) {
  __shared__ float rowbuf[8][1536];
  const int r0 = blockIdx.x * 8;
  const int tid = threadIdx.x;
  for (int idx = tid; idx < 8 * 1536; idx += 256) {
    const int rr = idx / 1536, k = idx % 1536;
    rowbuf[rr][k] = __bfloat162float(Hs[(size_t)(r0 + rr) * H2 + k]);
  }
  __syncthreads();
  const int l = tid & 31, rr = tid >> 5;
  float acc = bout[l];
  #pragma unroll 8
  for (int k = 0; k < 1536; ++k) acc += rowbuf[rr][k] * Wout[k * 32 + l];
  const int row = r0 + rr;
  if (l == 0 && tokens[row] == 1) acc += 10000.0f;
  out[(size_t)row * 32 + l] = acc;
}

// ---------------- host launcher ----------------
extern "C" void kernel_launch(void* const* d_in, const int* in_sizes, int n_in,
                              void* d_out, int out_size, void* d_ws, size_t ws_size,
                              hipStream_t stream) {
  const int*   tokens = (const int*)d_in[0];
  const float* emb    = (const float*)d_in[2];
  const float* Wi_f   = (const float*)d_in[3];
  const float* bi_f   = (const float*)d_in[4];
  const float* Wh_f   = (const float*)d_in[5];
  const float* bh_f   = (const float*)d_in[6];
  const float* Wi_b   = (const float*)d_in[7];
  const float* bi_b   = (const float*)d_in[8];
  const float* Wh_b   = (const float*)d_in[9];
  const float* bh_b   = (const float*)d_in[10];
  const float* Wout   = (const float*)d_in[11];
  const float* bout   = (const float*)d_in[12];
  float* out = (float*)d_out;
  char* ws = (char*)d_ws;

  size_t off = 0;
  auto alloc = [&](size_t bytes) { size_t o = off; off += (bytes + 255) & ~(size_t)255; return o; };
  const size_t oHs    = alloc((size_t)M_ROWS * H2 * 2);        // 100.7 MB
  const size_t oX     = alloc((size_t)CM * G4 * 2);            // 50.3 MB
  const size_t oEmb   = alloc((size_t)M_ROWS * E_DIM * 2);     // 33.6 MB
  const size_t oWiT   = alloc((size_t)G4 * E_DIM * 2);         // 3.1 MB
  const size_t oWhTf  = alloc((size_t)G4 * H_DIM * 2);         // 4.7 MB
  const size_t oBias  = alloc((size_t)G4 * 4);
  const size_t oHbuf  = alloc((size_t)2 * PSTR * 8);           // 256 KB packed h
  const size_t oCst   = alloc((size_t)B_DIM * H_DIM * 4);
  const size_t oHT    = alloc((size_t)B_DIM * H_DIM * 4);
  const size_t oHTW   = alloc((size_t)B_DIM * G4 * 4);
  const size_t oC2    = alloc((size_t)B_DIM * H_DIM * 4);
  (void)ws_size; (void)in_sizes; (void)n_in; (void)out_size;

  __hip_bfloat16* Hs   = (__hip_bfloat16*)(ws + oHs);
  __hip_bfloat16* X    = (__hip_bfloat16*)(ws + oX);
  __hip_bfloat16* Emb  = (__hip_bfloat16*)(ws + oEmb);
  __hip_bfloat16* WiT  = (__hip_bfloat16*)(ws + oWiT);
  __hip_bfloat16* WhTf = (__hip_bfloat16*)(ws + oWhTf);
  float*          Bias = (float*)(ws + oBias);
  ull_t*          Hbuf = (ull_t*)(ws + oHbuf);
  float*          Cst  = (float*)(ws + oCst);
  float*          HT   = (float*)(ws + oHT);
  float*          HTW  = (float*)(ws + oHTW);
  float*          C2   = (float*)(ws + oC2);

  hipMemsetAsync(ws + oHbuf, 0, (size_t)2 * PSTR * 8, stream);   // h_0 = 0, tag 0
  hipMemsetAsync(ws + oCst, 0, (size_t)B_DIM * H_DIM * 4, stream);
  hipMemsetAsync(ws + oC2, 0, (size_t)B_DIM * H_DIM * 4, stream);

  k_gather<<<8192, 256, 0, stream>>>(tokens, emb, Emb);
  k_transpose_cast<<<dim3(96, 24), 256, 0, stream>>>(Wh_f, WhTf, 768, 3072);

  // ---- forward direction: 4 chunks of (GEMM -> scan) ----
  k_transpose_cast<<<dim3(96, 16), 256, 0, stream>>>(Wi_f, WiT, 512, 3072);
  k_bias<<<12, 256, 0, stream>>>(bi_f, bh_f, Bias);
  for (int c = 0; c < 4; ++c) {
    k_gemm_x<<<dim3(24, 64), 256, 0, stream>>>(Emb + (size_t)c * CM * E_DIM, WiT, Bias, X);
    k_fwd_scan<<<64, 256, 0, stream>>>(X, WhTf, Hbuf, Hs, Cst, HT, c);
  }

  // ---- backward direction: hT@Wh_b once, then 4 chunks in reverse ----
  k_hTW<<<dim3(12, 64), 256, 0, stream>>>(HT, Wh_b, HTW);
  k_transpose_cast<<<dim3(96, 16), 256, 0, stream>>>(Wi_b, WiT, 512, 3072);
  k_bias<<<12, 256, 0, stream>>>(bi_b, bh_b, Bias);
  for (int c = 3; c >= 0; --c) {
    k_gemm_x<<<dim3(24, 64), 256, 0, stream>>>(Emb + (size_t)c * CM * E_DIM, WiT, Bias, X);
    k_bwd_scan<<<192, 256, 0, stream>>>(X, HTW, Hs, C2, c);
  }

  k_out<<<4096, 256, 0, stream>>>(Hs, Wout, bout, tokens, out);
}

// Round 4
// 3186.847 us; speedup vs baseline: 1.5073x; 1.3281x over previous
//
#include <hip/hip_runtime.h>
#include <hip/hip_bf16.h>
#include <stdint.h>

typedef __attribute__((ext_vector_type(8))) short bf16x8;
typedef __attribute__((ext_vector_type(4))) float f32x4;
typedef __attribute__((ext_vector_type(4))) unsigned int u32x4;
typedef unsigned long long ull_t;

#define S_LEN 512
#define B_DIM 64
#define E_DIM 512
#define H_DIM 768
#define G4    3072      // 4H (one direction's gate width)
#define H2    1536      // 2H (combined hs row)
#define M_ROWS 32768    // S*B
#define CHUNK 128       // seq steps per X-chunk
#define CM    8192      // CHUNK*B rows per chunk
#define SLW   24        // cols per slice
#define WPS   8         // published words per slice per row
#define WPR   256       // packed words per h row (256*3 = 768 cols)
#define RWRD  4096      // words per ring per parity (16 rows * 256)
#define PSTR  16384     // words per parity (4 rings)
#define KRES  640       // K columns resident in LDS
#define KREG  4         // K-tail tiles in registers (4*32 = 128)
#define WROW  648       // padded LDS weight row (shorts)

__device__ __forceinline__ float sigmf_(float x) { return 1.0f / (1.0f + __expf(-x)); }
__device__ __forceinline__ float tanhf2(float x) {
  x = fminf(fmaxf(x, -20.0f), 20.0f);
  float e = __expf(2.0f * x);
  return (e - 1.0f) / (e + 1.0f);
}
__device__ __forceinline__ float bfu(unsigned short u) { return __uint_as_float((unsigned)u << 16); }
__device__ __forceinline__ unsigned short packbf(float a) {
  __hip_bfloat16 t = __float2bfloat16(a);
  unsigned short b;
  __builtin_memcpy(&b, &t, 2);
  return b;
}

// ---------------- embedding gather + cast to bf16 ----------------
__global__ __launch_bounds__(256) void k_gather(const int* __restrict__ tokens,
                                                const float* __restrict__ emb,
                                                __hip_bfloat16* __restrict__ out) {
  const int t = blockIdx.x * 256 + threadIdx.x;
  const int e0 = t * 8;
  const int row = e0 >> 9;
  const int k = e0 & 511;
  const int tok = tokens[row];
  const float4* p = (const float4*)(emb + (size_t)tok * E_DIM + k);
  const float4 v0 = p[0], v1 = p[1];
  __align__(16) __hip_bfloat16 tmp[8];
  tmp[0] = __float2bfloat16(v0.x); tmp[1] = __float2bfloat16(v0.y);
  tmp[2] = __float2bfloat16(v0.z); tmp[3] = __float2bfloat16(v0.w);
  tmp[4] = __float2bfloat16(v1.x); tmp[5] = __float2bfloat16(v1.y);
  tmp[6] = __float2bfloat16(v1.z); tmp[7] = __float2bfloat16(v1.w);
  *(bf16x8*)(out + (size_t)t * 8) = *(const bf16x8*)tmp;
}

// ---------------- fp32 -> bf16 transpose (LDS tiled): dst[c*Rs+r]=src[r*Cs+c] ----------------
__global__ __launch_bounds__(256) void k_transpose_cast(const float* __restrict__ src,
                                                        __hip_bfloat16* __restrict__ dst,
                                                        int Rs, int Cs) {
  __shared__ float tile[32][33];
  const int tx = threadIdx.x & 31, ty = threadIdx.x >> 5;
  const int c0 = blockIdx.x * 32, r0 = blockIdx.y * 32;
  #pragma unroll
  for (int i = ty; i < 32; i += 8)
    tile[i][tx] = src[(size_t)(r0 + i) * Cs + c0 + tx];
  __syncthreads();
  #pragma unroll
  for (int i = ty; i < 32; i += 8)
    dst[(size_t)(c0 + i) * Rs + r0 + tx] = __float2bfloat16(tile[tx][i]);
}

// ---------------- combined bias for one direction: bi + bh ----------------
__global__ __launch_bounds__(256) void k_bias(const float* __restrict__ bi,
                                              const float* __restrict__ bh,
                                              float* __restrict__ bias) {
  const int n = blockIdx.x * 256 + threadIdx.x;
  bias[n] = bi[n] + bh[n];
}

// ---------------- chunk GEMM: Xc[8192,3072] = EmbChunk[8192,512] @ WiT^T + bias ----------------
__global__ __launch_bounds__(256) void k_gemm_x(const __hip_bfloat16* __restrict__ A,
                                                const __hip_bfloat16* __restrict__ BT,
                                                const float* __restrict__ bias,
                                                __hip_bfloat16* __restrict__ C) {
  __shared__ __align__(16) __hip_bfloat16 As[128][40];
  __shared__ __align__(16) __hip_bfloat16 Bs[128][40];
  const int tid = threadIdx.x;
  const int wave = tid >> 6, lane = tid & 63;
  const int q = lane >> 4, lr = lane & 15;
  const int wm = (wave >> 1) * 64, wn = (wave & 1) * 64;
  const int m0 = blockIdx.y * 128, n0 = blockIdx.x * 128;
  const int srow = tid >> 2, skseg = (tid & 3) * 8;

  f32x4 acc[4][4];
  #pragma unroll
  for (int i = 0; i < 4; ++i)
    #pragma unroll
    for (int j = 0; j < 4; ++j) { f32x4 z = {0.f, 0.f, 0.f, 0.f}; acc[i][j] = z; }

  for (int kt = 0; kt < 16; ++kt) {
    __syncthreads();
    const int kbase = kt * 32 + skseg;
    *(bf16x8*)&As[srow][skseg]      = *(const bf16x8*)(A + (size_t)(m0 + srow) * E_DIM + kbase);
    *(bf16x8*)&As[srow + 64][skseg] = *(const bf16x8*)(A + (size_t)(m0 + srow + 64) * E_DIM + kbase);
    *(bf16x8*)&Bs[srow][skseg]      = *(const bf16x8*)(BT + (size_t)(n0 + srow) * E_DIM + kbase);
    *(bf16x8*)&Bs[srow + 64][skseg] = *(const bf16x8*)(BT + (size_t)(n0 + srow + 64) * E_DIM + kbase);
    __syncthreads();
    bf16x8 af[4], bfr[4];
    #pragma unroll
    for (int mt = 0; mt < 4; ++mt) af[mt] = *(const bf16x8*)&As[wm + mt * 16 + lr][q * 8];
    #pragma unroll
    for (int nt = 0; nt < 4; ++nt) bfr[nt] = *(const bf16x8*)&Bs[wn + nt * 16 + lr][q * 8];
    #pragma unroll
    for (int mt = 0; mt < 4; ++mt)
      #pragma unroll
      for (int nt = 0; nt < 4; ++nt)
        acc[mt][nt] = __builtin_amdgcn_mfma_f32_16x16x32_bf16(af[mt], bfr[nt], acc[mt][nt], 0, 0, 0);
  }
  #pragma unroll
  for (int mt = 0; mt < 4; ++mt) {
    #pragma unroll
    for (int nt = 0; nt < 4; ++nt) {
      const int col = n0 + wn + nt * 16 + lr;
      const float bv = bias[col];
      #pragma unroll
      for (int i = 0; i < 4; ++i) {
        const int row = m0 + wm + mt * 16 + q * 4 + i;
        C[(size_t)row * G4 + col] = __float2bfloat16(acc[mt][nt][i] + bv);
      }
    }
  }
}

// ---------------- forward LSTM scan: tag-in-data systolic, wide coherent polls ----------
// 128 WGs = 4 rings (16 batch rows) x 32 col-slices (24 cols = 8 words/row).
// Protocol identical to the verified R1 kernel (tag-in-data, 1 LLC round trip,
// double-buffer safety by stage->produce phase order). New this round:
//  * poll via global_load_dwordx4 sc0 sc1 (16B = 2 tagged words), pair-interleaved
//    ownership {2pw+32i} -> per-instruction 64 lanes read 4x256B contiguous:
//    full-line LLC transactions, 8 instrs/thread (was 16x8B, ~8x amplified).
//  * self-slice short-circuit: publishers copy their own h into h_stage locally
//    after B2; pollers skip the own-slice pair (except first step of a chunk).
//  * staging = 3x ds_write_b32 per pair (no b16 scatter).
// Weights: KRES=640 cols in LDS + KREG=4 tail tiles in 32 VGPRs (the config the
// compiler provably keeps resident: R1 VGPR_Count=132).
__global__ __launch_bounds__(256, 1) void k_fwd_scan(const __hip_bfloat16* __restrict__ X,    // [8192,3072] chunk
                                                     const __hip_bfloat16* __restrict__ WhTf, // [3072,768]
                                                     ull_t* __restrict__ hbuf,                // [2][4][16][256]
                                                     __hip_bfloat16* __restrict__ Hs,         // [32768,1536]
                                                     float* __restrict__ cstate,              // [64,768]
                                                     float* __restrict__ hT,                  // [64,768]
                                                     int chunk) {
  const int bx = blockIdx.x;
  const int group = bx >> 5;           // ring: batch rows [16g, 16g+16)
  const int slice = bx & 31;           // cols [24*slice, 24*slice+24)
  const int r0 = group * 16;
  const int j0 = slice * SLW;
  const int tid = threadIdx.x;
  const int w = tid >> 6;              // wave = gate index (r,f,g,o)
  const int lane = tid & 63;
  const int q = lane >> 4, lr = lane & 15;
  const int base = chunk * CHUNK;

  const int prow = tid >> 4;           // poll: batch row within group (0..15)
  const int pw   = tid & 15;           // poll: pair lane (0..15)

  const int row  = tid >> 3;           // publisher row (tid<128): 0..15
  const int wloc = tid & 7;            // publisher word within slice
  const int col0 = 3 * wloc;           // first owned col within slice

  __shared__ __align__(16) unsigned short wlds[4 * SLW * WROW];  // 124,416 B weight slice
  __shared__ __align__(16) unsigned short h_stage[16][776];      //  24,832 B
  __shared__ float g_lds[4][16][26];                             //   6,656 B (total 155,904)

  // ---- stage LDS-resident weights once ----
  for (int c = tid; c < 96 * (KRES / 8); c += 256) {
    const int r = c / (KRES / 8), k8 = c % (KRES / 8);
    const int gate = r / SLW, n = r % SLW;
    const float4 v = *(const float4*)(WhTf + (size_t)(gate * H_DIM + j0 + n) * H_DIM + k8 * 8);
    *(float4*)(wlds + (size_t)r * WROW + k8 * 8) = v;
  }

  // ---- K-tail weight fragments pinned in registers (step-invariant, 32 VGPRs) ----
  const int wn0 = lr;                  // n-tile 0: cols 0..15
  const int wn1 = 16 + (lr & 7);       // n-tile 1: cols 16..23 (lanes lr>=8 duplicate)
  bf16x8 wr0[KREG], wr1[KREG];
  #pragma unroll
  for (int kk = 0; kk < KREG; ++kk) {
    const int ko = KRES + kk * 32 + q * 8;
    wr0[kk] = *(const bf16x8*)(WhTf + (size_t)(w * H_DIM + j0 + wn0) * H_DIM + ko);
    wr1[kk] = *(const bf16x8*)(WhTf + (size_t)(w * H_DIM + j0 + wn1) * H_DIM + ko);
  }

  // persistent c in registers: thread (tid<128) owns (row, col0..col0+2)
  float cr[3] = {0.f, 0.f, 0.f};
  if (tid < 128) {
    const float* cs = cstate + (size_t)(r0 + row) * H_DIM + j0 + col0;
    cr[0] = cs[0]; cr[1] = cs[1]; cr[2] = cs[2];
  }

  // own-slice pair in this thread's poll set: words [8*slice, 8*slice+8) fall in
  // pair i0 = slice>>2 for threads with pw>>2 == slice&3
  const unsigned skipbit = ((pw >> 2) == (slice & 3)) ? (1u << (slice >> 2)) : 0u;

  __syncthreads();

  for (int s = 0; s < CHUNK; ++s) {
    const int gs = base + s;

    // ---- X loads for this step (independent of h; overlap the poll) ----
    unsigned short xs[4][3];
    if (tid < 128) {
      const unsigned short* xp = (const unsigned short*)(X + ((size_t)s * B_DIM + r0 + row) * G4 + j0 + col0);
      #pragma unroll
      for (int g = 0; g < 4; ++g)
        #pragma unroll
        for (int j = 0; j < 3; ++j) xs[g][j] = xp[g * H_DIM + j];
    }

    // ---- poll: 8x 16B coherent loads (2 tagged words each), pair-interleaved ----
    const ull_t* hc = hbuf + ((size_t)(gs & 1)) * PSTR + (size_t)group * RWRD
                    + (size_t)prow * WPR + 2 * pw;
    u32x4 d0 = {0,0,0,0}, d1 = {0,0,0,0}, d2 = {0,0,0,0}, d3 = {0,0,0,0};
    u32x4 d4 = {0,0,0,0}, d5 = {0,0,0,0}, d6 = {0,0,0,0}, d7 = {0,0,0,0};
    const unsigned pollmask = (s == 0) ? 0xFFu : (0xFFu ^ skipbit);
    {
      const unsigned e16 = (unsigned)(unsigned short)gs;
      unsigned need = pollmask;
      long guard = 0;
      for (;;) {
#define POLL_LD(i, dv) \
        if (need & (1u << (i))) \
          asm volatile("global_load_dwordx4 %0, %1, off sc0 sc1" \
                       : "=v"(dv) : "v"(hc + 32 * (i)) : "memory");
        POLL_LD(0, d0) POLL_LD(1, d1) POLL_LD(2, d2) POLL_LD(3, d3)
        POLL_LD(4, d4) POLL_LD(5, d5) POLL_LD(6, d6) POLL_LD(7, d7)
#undef POLL_LD
        asm volatile("s_waitcnt vmcnt(0)"
                     : "+v"(d0), "+v"(d1), "+v"(d2), "+v"(d3),
                       "+v"(d4), "+v"(d5), "+v"(d6), "+v"(d7)
                     :: "memory");
        unsigned nn = 0;
#define POLL_CK(i, dv) \
        if ((need & (1u << (i))) && \
            ((((dv).x & 0xFFFFu) != e16) || (((dv).z & 0xFFFFu) != e16))) nn |= 1u << (i);
        POLL_CK(0, d0) POLL_CK(1, d1) POLL_CK(2, d2) POLL_CK(3, d3)
        POLL_CK(4, d4) POLL_CK(5, d5) POLL_CK(6, d6) POLL_CK(7, d7)
#undef POLL_CK
        need = nn;
        if (!need) break;
        if (++guard > (1L << 20)) break;   // fail visibly, never hang
        __builtin_amdgcn_s_sleep(1);
      }
    }
    // ---- strip tags, stage each pair as 3x b32 at short-offset 6*pw+96*i ----
    {
#define STAGE_PAIR(i, dv) \
      if (pollmask & (1u << (i))) { \
        unsigned* hp = (unsigned*)&h_stage[prow][6 * pw + 96 * (i)]; \
        hp[0] = ((dv).x >> 16) | ((dv).y << 16); \
        hp[1] = ((dv).y >> 16) | ((dv).z & 0xFFFF0000u); \
        hp[2] = (dv).w; \
      }
      STAGE_PAIR(0, d0) STAGE_PAIR(1, d1) STAGE_PAIR(2, d2) STAGE_PAIR(3, d3)
      STAGE_PAIR(4, d4) STAGE_PAIR(5, d5) STAGE_PAIR(6, d6) STAGE_PAIR(7, d7)
#undef STAGE_PAIR
    }
    __syncthreads();   // B1: h staged

    // ---- hidden GEMM for gate w: [16,768] x [768,24] from LDS + reg weights ----
    f32x4 acc0 = {0.f, 0.f, 0.f, 0.f};
    f32x4 acc1 = {0.f, 0.f, 0.f, 0.f};
    {
      const unsigned short* wb = wlds + (size_t)w * SLW * WROW;
      #pragma unroll
      for (int kt = 0; kt < KRES / 32; ++kt) {
        const int ko = kt * 32 + q * 8;
        const bf16x8 a  = *(const bf16x8*)&h_stage[lr][ko];
        const bf16x8 b0 = *(const bf16x8*)(wb + (size_t)wn0 * WROW + ko);
        const bf16x8 b1 = *(const bf16x8*)(wb + (size_t)wn1 * WROW + ko);
        acc0 = __builtin_amdgcn_mfma_f32_16x16x32_bf16(a, b0, acc0, 0, 0, 0);
        acc1 = __builtin_amdgcn_mfma_f32_16x16x32_bf16(a, b1, acc1, 0, 0, 0);
      }
      #pragma unroll
      for (int kk = 0; kk < KREG; ++kk) {
        const bf16x8 a = *(const bf16x8*)&h_stage[lr][KRES + kk * 32 + q * 8];
        acc0 = __builtin_amdgcn_mfma_f32_16x16x32_bf16(a, wr0[kk], acc0, 0, 0, 0);
        acc1 = __builtin_amdgcn_mfma_f32_16x16x32_bf16(a, wr1[kk], acc1, 0, 0, 0);
      }
    }
    #pragma unroll
    for (int i = 0; i < 4; ++i) g_lds[w][q * 4 + i][lr] = acc0[i];
    if (lr < 8) {
      #pragma unroll
      for (int i = 0; i < 4; ++i) g_lds[w][q * 4 + i][16 + lr] = acc1[i];
    }
    __syncthreads();   // B2: gates ready

    // ---- nonlinearity + c/h update + publish: thread owns (row, col0..col0+2) ----
    if (tid < 128) {
      float h[3];
      #pragma unroll
      for (int j = 0; j < 3; ++j) {
        const float rv = g_lds[0][row][col0 + j] + bfu(xs[0][j]);
        const float fv = g_lds[1][row][col0 + j] + bfu(xs[1][j]);
        const float gv = g_lds[2][row][col0 + j] + bfu(xs[2][j]);
        const float ov = g_lds[3][row][col0 + j] + bfu(xs[3][j]);
        const float c = sigmf_(fv) * cr[j] + sigmf_(rv) * tanhf2(gv);
        cr[j] = c;
        h[j] = sigmf_(ov) * tanhf2(c);
      }
      const unsigned short b0 = packbf(h[0]), b1 = packbf(h[1]), b2 = packbf(h[2]);
      const ull_t wv = (ull_t)(unsigned short)(gs + 1)
                     | ((ull_t)b0 << 16) | ((ull_t)b1 << 32) | ((ull_t)b2 << 48);
      __hip_atomic_store(hbuf + ((size_t)((gs + 1) & 1)) * PSTR + (size_t)group * RWRD
                         + (size_t)row * WPR + slice * WPS + wloc,
                         wv, __ATOMIC_RELAXED, __HIP_MEMORY_SCOPE_AGENT);
      // self-slice short-circuit: local copy for next step's h_stage
      // (h_stage is dead between B2 and the next B1; disjoint from poller writes)
      h_stage[row][j0 + col0]     = b0;
      h_stage[row][j0 + col0 + 1] = b1;
      h_stage[row][j0 + col0 + 2] = b2;
      unsigned short* hsp = (unsigned short*)(Hs + ((size_t)gs * B_DIM + r0 + row) * H2 + j0 + col0);
      hsp[0] = b0; hsp[1] = b1; hsp[2] = b2;
      if (chunk == 3 && s == CHUNK - 1) {
        float* hp = hT + (size_t)(r0 + row) * H_DIM + j0 + col0;
        hp[0] = h[0]; hp[1] = h[1]; hp[2] = h[2];
      }
    }
    // no barrier: next step's B1 orders h_stage/g_lds reuse
  }

  // persist c for next chunk
  if (tid < 128) {
    float* cs = cstate + (size_t)(r0 + row) * H_DIM + j0 + col0;
    cs[0] = cr[0]; cs[1] = cr[1]; cs[2] = cr[2];
  }
}

// ---------------- hTW[b,n] = hT[b,:] @ Wh_b[:,n] ----------------
__global__ __launch_bounds__(256) void k_hTW(const float* __restrict__ hT,
                                             const float* __restrict__ Whb,
                                             float* __restrict__ hTW) {
  const int b = blockIdx.y;
  const int n = blockIdx.x * 256 + threadIdx.x;
  __shared__ float hs[768];
  for (int i = threadIdx.x; i < 768; i += 256) hs[i] = hT[b * 768 + i];
  __syncthreads();
  float acc = 0.f;
  #pragma unroll 4
  for (int k = 0; k < 768; ++k) acc += hs[k] * Whb[(size_t)k * G4 + n];
  hTW[(size_t)b * G4 + n] = acc;
}

// ---------------- backward scan (one chunk, reverse): independent chains ----------------
__global__ __launch_bounds__(256) void k_bwd_scan(const __hip_bfloat16* __restrict__ X,
                                                  const float* __restrict__ hTW,
                                                  __hip_bfloat16* __restrict__ Hs,
                                                  float* __restrict__ c2state,
                                                  int chunk) {
  const int t = blockIdx.x * 256 + threadIdx.x;    // 49152
  const int b = t / H_DIM;
  const int j = t % H_DIM;
  const int base = chunk * CHUNK;
  const float hw0 = hTW[(size_t)b * G4 + j];
  const float hw1 = hTW[(size_t)b * G4 + 768 + j];
  const float hw2 = hTW[(size_t)b * G4 + 1536 + j];
  const float hw3 = hTW[(size_t)b * G4 + 2304 + j];
  float c2 = c2state[t];
  for (int s = CHUNK - 1; s >= 0; --s) {
    const size_t xb = ((size_t)s * B_DIM + b) * G4 + j;
    const float r = sigmf_(__bfloat162float(X[xb]) + hw0);
    const float f = sigmf_(__bfloat162float(X[xb + 768]) + hw1);
    const float g = tanhf2(__bfloat162float(X[xb + 1536]) + hw2);
    const float o = sigmf_(__bfloat162float(X[xb + 2304]) + hw3);
    c2 = f * c2 + r * g;
    Hs[((size_t)(base + s) * B_DIM + b) * H2 + H_DIM + j] = __float2bfloat16(o * tanhf2(c2));
  }
  c2state[t] = c2;
}

// ---------------- output: out[i,l] = Hs[i,:] @ Wout + bout (+pad bias) ----------------
__global__ __launch_bounds__(256) void k_out(const __hip_bfloat16* __restrict__ Hs,
                                             const float* __restrict__ Wout,
                                             const float* __restrict__ bout,
                                             const int* __restrict__ tokens,
                                             float* __restrict__ out) {
  __shared__ float rowbuf[8][1536];
  const int r0 = blockIdx.x * 8;
  const int tid = threadIdx.x;
  for (int idx = tid; idx < 8 * 1536; idx += 256) {
    const int rr = idx / 1536, k = idx % 1536;
    rowbuf[rr][k] = __bfloat162float(Hs[(size_t)(r0 + rr) * H2 + k]);
  }
  __syncthreads();
  const int l = tid & 31, rr = tid >> 5;
  float acc = bout[l];
  #pragma unroll 8
  for (int k = 0; k < 1536; ++k) acc += rowbuf[rr][k] * Wout[k * 32 + l];
  const int row = r0 + rr;
  if (l == 0 && tokens[row] == 1) acc += 10000.0f;
  out[(size_t)row * 32 + l] = acc;
}

// ---------------- host launcher ----------------
extern "C" void kernel_launch(void* const* d_in, const int* in_sizes, int n_in,
                              void* d_out, int out_size, void* d_ws, size_t ws_size,
                              hipStream_t stream) {
  const int*   tokens = (const int*)d_in[0];
  const float* emb    = (const float*)d_in[2];
  const float* Wi_f   = (const float*)d_in[3];
  const float* bi_f   = (const float*)d_in[4];
  const float* Wh_f   = (const float*)d_in[5];
  const float* bh_f   = (const float*)d_in[6];
  const float* Wi_b   = (const float*)d_in[7];
  const float* bi_b   = (const float*)d_in[8];
  const float* Wh_b   = (const float*)d_in[9];
  const float* bh_b   = (const float*)d_in[10];
  const float* Wout   = (const float*)d_in[11];
  const float* bout   = (const float*)d_in[12];
  float* out = (float*)d_out;
  char* ws = (char*)d_ws;

  size_t off = 0;
  auto alloc = [&](size_t bytes) { size_t o = off; off += (bytes + 255) & ~(size_t)255; return o; };
  const size_t oHs    = alloc((size_t)M_ROWS * H2 * 2);        // 100.7 MB
  const size_t oX     = alloc((size_t)CM * G4 * 2);            // 50.3 MB
  const size_t oEmb   = alloc((size_t)M_ROWS * E_DIM * 2);     // 33.6 MB
  const size_t oWiT   = alloc((size_t)G4 * E_DIM * 2);         // 3.1 MB
  const size_t oWhTf  = alloc((size_t)G4 * H_DIM * 2);         // 4.7 MB
  const size_t oBias  = alloc((size_t)G4 * 4);
  const size_t oHbuf  = alloc((size_t)2 * PSTR * 8);           // 256 KB packed h
  const size_t oCst   = alloc((size_t)B_DIM * H_DIM * 4);
  const size_t oHT    = alloc((size_t)B_DIM * H_DIM * 4);
  const size_t oHTW   = alloc((size_t)B_DIM * G4 * 4);
  const size_t oC2    = alloc((size_t)B_DIM * H_DIM * 4);
  (void)ws_size; (void)in_sizes; (void)n_in; (void)out_size;

  __hip_bfloat16* Hs   = (__hip_bfloat16*)(ws + oHs);
  __hip_bfloat16* X    = (__hip_bfloat16*)(ws + oX);
  __hip_bfloat16* Emb  = (__hip_bfloat16*)(ws + oEmb);
  __hip_bfloat16* WiT  = (__hip_bfloat16*)(ws + oWiT);
  __hip_bfloat16* WhTf = (__hip_bfloat16*)(ws + oWhTf);
  float*          Bias = (float*)(ws + oBias);
  ull_t*          Hbuf = (ull_t*)(ws + oHbuf);
  float*          Cst  = (float*)(ws + oCst);
  float*          HT   = (float*)(ws + oHT);
  float*          HTW  = (float*)(ws + oHTW);
  float*          C2   = (float*)(ws + oC2);

  hipMemsetAsync(ws + oHbuf, 0, (size_t)2 * PSTR * 8, stream);   // h_0 = 0, tag 0
  hipMemsetAsync(ws + oCst, 0, (size_t)B_DIM * H_DIM * 4, stream);
  hipMemsetAsync(ws + oC2, 0, (size_t)B_DIM * H_DIM * 4, stream);

  k_gather<<<8192, 256, 0, stream>>>(tokens, emb, Emb);
  k_transpose_cast<<<dim3(96, 24), 256, 0, stream>>>(Wh_f, WhTf, 768, 3072);

  // ---- forward direction: 4 chunks of (GEMM -> scan) ----
  k_transpose_cast<<<dim3(96, 16), 256, 0, stream>>>(Wi_f, WiT, 512, 3072);
  k_bias<<<12, 256, 0, stream>>>(bi_f, bh_f, Bias);
  for (int c = 0; c < 4; ++c) {
    k_gemm_x<<<dim3(24, 64), 256, 0, stream>>>(Emb + (size_t)c * CM * E_DIM, WiT, Bias, X);
    k_fwd_scan<<<128, 256, 0, stream>>>(X, WhTf, Hbuf, Hs, Cst, HT, c);
  }

  // ---- backward direction: hT@Wh_b once, then 4 chunks in reverse ----
  k_hTW<<<dim3(12, 64), 256, 0, stream>>>(HT, Wh_b, HTW);
  k_transpose_cast<<<dim3(96, 16), 256, 0, stream>>>(Wi_b, WiT, 512, 3072);
  k_bias<<<12, 256, 0, stream>>>(bi_b, bh_b, Bias);
  for (int c = 3; c >= 0; --c) {
    k_gemm_x<<<dim3(24, 64), 256, 0, stream>>>(Emb + (size_t)c * CM * E_DIM, WiT, Bias, X);
    k_bwd_scan<<<192, 256, 0, stream>>>(X, HTW, Hs, C2, c);
  }

  k_out<<<4096, 256, 0, stream>>>(Hs, Wout, bout, tokens, out);
}